// Round 1
// baseline (192.919 us; speedup 1.0000x reference)
//
#include <hip/hip_runtime.h>
#include <hip/hip_fp16.h>

typedef _Float16 half8 __attribute__((ext_vector_type(8)));
typedef float floatx4 __attribute__((ext_vector_type(4)));

#define LSEQ 512
#define DSTATE 256
#define DPAIR 128
#define HH 32
#define DRBF 36

#define MUSTEP (20.0f / 35.0f)   // linspace(2,22,36) step
#define INVSIG 1.8f              // 1 / ((22-2)/36)

// ---------------- Kernel A: layernorm(state) -> left (fp32), right (fp16) ----
__global__ __launch_bounds__(256) void prologA(
    const float* __restrict__ state, const float* __restrict__ ln_w,
    const float* __restrict__ ln_b, const float* __restrict__ w_left,
    const float* __restrict__ b_left, const float* __restrict__ w_right,
    const float* __restrict__ b_right, float* __restrict__ left,
    _Float16* __restrict__ right_h) {
  __shared__ float stS[DSTATE];
  __shared__ float redS[4], redQ[4];
  const int l = blockIdx.x, tid = threadIdx.x;

  float x = state[l * DSTATE + tid];
  float s = x, q = x * x;
  #pragma unroll
  for (int o = 32; o > 0; o >>= 1) {
    s += __shfl_down(s, o);
    q += __shfl_down(q, o);
  }
  if ((tid & 63) == 0) { redS[tid >> 6] = s; redQ[tid >> 6] = q; }
  __syncthreads();
  float tot = redS[0] + redS[1] + redS[2] + redS[3];
  float totq = redQ[0] + redQ[1] + redQ[2] + redQ[3];
  float mean = tot * (1.0f / DSTATE);
  float var = totq * (1.0f / DSTATE) - mean * mean;
  float inv = rsqrtf(var + 1e-5f);
  stS[tid] = (x - mean) * inv * ln_w[tid] + ln_b[tid];
  __syncthreads();

  if (tid < HH) {
    float acc = b_left[tid];
    for (int c = 0; c < DSTATE; ++c) acc += stS[c] * w_left[c * HH + tid];
    left[l * HH + tid] = acc;
  } else if (tid >= 64 && tid < 64 + HH) {
    const int j = tid - 64;
    float acc = b_right[j];
    for (int c = 0; c < DSTATE; ++c) acc += stS[c] * w_right[c * HH + j];
    right_h[l * HH + j] = (_Float16)acc;
  }
}

// ---- Kernel B: tT[l][p][j] = sum_i left[l][i]*Wg[i][j][p] (fp16), + w_rbfT --
// grid: 128 blocks (16 jp-chunks x 8 l-chunks) + 1 block for w_rbfT
__global__ __launch_bounds__(256) void prologB(
    const float* __restrict__ w_gate, const float* __restrict__ w_rbf,
    const float* __restrict__ left, _Float16* __restrict__ tT,
    _Float16* __restrict__ w_rbfT) {
  const int tid = threadIdx.x;
  if (blockIdx.x == 128) {
    // w_rbfT[p][k] (128 x 64), zero-padded k in [36,64)
    for (int e = tid; e < DPAIR * 64; e += 256) {
      int p = e >> 6, k = e & 63;
      w_rbfT[e] = (k < DRBF) ? (_Float16)w_rbf[k * DPAIR + p] : (_Float16)0.0f;
    }
    return;
  }
  const int c = blockIdx.x & 15;   // jp-chunk (256 columns)
  const int lc = blockIdx.x >> 4;  // l-chunk (64 rows)
  const int j = tid & 31;
  const int p = c * 8 + (tid >> 5);

  float wcol[32];
  #pragma unroll
  for (int i = 0; i < 32; ++i) wcol[i] = w_gate[(i * HH + j) * DPAIR + p];

  const int l0 = lc * 64;
  for (int l = l0; l < l0 + 64; ++l) {
    const float* __restrict__ lf = left + l * HH;  // wave-uniform -> s_loads
    float acc = 0.0f;
    #pragma unroll
    for (int i = 0; i < 32; ++i) acc += lf[i] * wcol[i];
    tT[l * (DPAIR * HH) + c * 256 + tid] = (_Float16)acc;
  }
}

// ---------------- Kernel C: main fused MFMA kernel ---------------------------
// grid 1024: block -> (l = bx>>1, m-half = bx&1). 256 threads = 4 waves.
// Per wave: 4 m-tiles x 8 p-tiles, 3 MFMAs each (1 logits + 2 rbf).
__global__ __launch_bounds__(256, 3) void mainC(
    const float* __restrict__ xyz, const float* __restrict__ b_rbf,
    const float* __restrict__ b_gate, const _Float16* __restrict__ right_h,
    const _Float16* __restrict__ tT, const _Float16* __restrict__ w_rbfT,
    float* __restrict__ out) {
  const int l = blockIdx.x >> 1;
  const int half = blockIdx.x & 1;
  const int tid = threadIdx.x;
  const int wave = tid >> 6;
  const int lane = tid & 63;
  const int ln16 = lane & 15;
  const int quad = lane >> 4;

  // cas_l (row a=1 of xyz[l])
  const float clx = xyz[l * 9 + 3];
  const float cly = xyz[l * 9 + 4];
  const float clz = xyz[l * 9 + 5];

  // Preload B-fragments for all 8 p-tiles (held in registers)
  half8 Bt[8], Bw0[8], Bw1[8];
  float bg[8], br[8];
  const _Float16* tTl = tT + (size_t)l * (DPAIR * HH);
  #pragma unroll
  for (int pt = 0; pt < 8; ++pt) {
    const int p = pt * 16 + ln16;
    Bt[pt] = *(const half8*)(tTl + p * HH + quad * 8);
    Bw0[pt] = *(const half8*)(w_rbfT + p * 64 + quad * 8);
    Bw1[pt] = *(const half8*)(w_rbfT + p * 64 + 32 + quad * 8);
    bg[pt] = b_gate[p];
    br[pt] = b_rbf[p];
  }

  const int mt0 = half * 16;
  for (int mt = mt0 + wave; mt < mt0 + 16; mt += 4) {
    const int mA = mt * 16 + ln16;  // A-operand row for this lane
    // right A-fragment (global, L2-hot)
    half8 Ar = *(const half8*)(right_h + mA * HH + quad * 8);

    // rbf A-fragments computed in registers (MFMA A-layout)
    const float dx = clx - xyz[mA * 9 + 3];
    const float dy = cly - xyz[mA * 9 + 4];
    const float dz = clz - xyz[mA * 9 + 5];
    const float d = sqrtf(fmaxf(dx * dx + dy * dy + dz * dz, 1e-12f));

    half8 A0, A1;
    #pragma unroll
    for (int jj = 0; jj < 8; ++jj) {
      const int k = quad * 8 + jj;
      const float u = (d - (2.0f + (float)k * MUSTEP)) * INVSIG;
      A0[jj] = (_Float16)__expf(-u * u);
    }
    #pragma unroll
    for (int jj = 0; jj < 8; ++jj) {
      const int k = 32 + quad * 8 + jj;
      float v = 0.0f;
      if (k < DRBF) {
        const float u = (d - (2.0f + (float)k * MUSTEP)) * INVSIG;
        v = __expf(-u * u);
      }
      A1[jj] = (_Float16)v;
    }

    #pragma unroll
    for (int pt = 0; pt < 8; ++pt) {
      floatx4 accL = {0.f, 0.f, 0.f, 0.f};
      floatx4 accR = {0.f, 0.f, 0.f, 0.f};
      accL = __builtin_amdgcn_mfma_f32_16x16x32_f16(Ar, Bt[pt], accL, 0, 0, 0);
      accR = __builtin_amdgcn_mfma_f32_16x16x32_f16(A0, Bw0[pt], accR, 0, 0, 0);
      accR = __builtin_amdgcn_mfma_f32_16x16x32_f16(A1, Bw1[pt], accR, 0, 0, 0);

      const int p = pt * 16 + ln16;
      float* orow = out + ((size_t)l * LSEQ + mt * 16 + quad * 4) * DPAIR + p;
      #pragma unroll
      for (int i = 0; i < 4; ++i) {
        const float logit = accL[i] + bg[pt];
        const float gate = __builtin_amdgcn_rcpf(1.0f + __expf(-logit));
        const float feat = accR[i] + br[pt];
        orow[i * DPAIR] = gate * feat;
      }
    }
  }
}

// ---------------- launch -----------------------------------------------------
extern "C" void kernel_launch(void* const* d_in, const int* in_sizes, int n_in,
                              void* d_out, int out_size, void* d_ws,
                              size_t ws_size, hipStream_t stream) {
  const float* xyz = (const float*)d_in[0];
  const float* state = (const float*)d_in[1];
  const float* ln_w = (const float*)d_in[2];
  const float* ln_b = (const float*)d_in[3];
  const float* w_rbf = (const float*)d_in[4];
  const float* b_rbf = (const float*)d_in[5];
  const float* w_left = (const float*)d_in[6];
  const float* b_left = (const float*)d_in[7];
  const float* w_right = (const float*)d_in[8];
  const float* b_right = (const float*)d_in[9];
  const float* w_gate = (const float*)d_in[10];
  const float* b_gate = (const float*)d_in[11];
  float* out = (float*)d_out;

  char* ws = (char*)d_ws;
  float* left = (float*)ws;                           // 512*32*4   = 65536 B
  _Float16* right_h = (_Float16*)(ws + 65536);        // 512*32*2   = 32768 B
  _Float16* tT = (_Float16*)(ws + 98304);             // 512*128*32*2 = 4 MB
  _Float16* w_rbfT = (_Float16*)(ws + 4292608);       // 128*64*2   = 16384 B

  prologA<<<512, 256, 0, stream>>>(state, ln_w, ln_b, w_left, b_left, w_right,
                                   b_right, left, right_h);
  prologB<<<129, 256, 0, stream>>>(w_gate, w_rbf, left, tT, w_rbfT);
  mainC<<<1024, 256, 0, stream>>>(xyz, b_rbf, b_gate, right_h, tT, w_rbfT, out);
}

// Round 2
// 190.230 us; speedup vs baseline: 1.0141x; 1.0141x over previous
//
#include <hip/hip_runtime.h>
#include <hip/hip_fp16.h>

typedef _Float16 half8 __attribute__((ext_vector_type(8)));
typedef float floatx4 __attribute__((ext_vector_type(4)));

#define LSEQ 512
#define DSTATE 256
#define DPAIR 128
#define HH 32
#define DRBF 36

#define MUSTEP (20.0f / 35.0f)   // linspace(2,22,36) step
#define INVSIG 1.8f              // 1 / ((22-2)/36)

// ---------------- Kernel A: layernorm(state) -> left (fp32), right (fp16) ----
// 512 blocks (one per l), 256 threads. Phase 2: 4 partial threads per output
// column (64 outputs = 32 left + 32 right), LDS reduce.
__global__ __launch_bounds__(256) void prologA(
    const float* __restrict__ state, const float* __restrict__ ln_w,
    const float* __restrict__ ln_b, const float* __restrict__ w_left,
    const float* __restrict__ b_left, const float* __restrict__ w_right,
    const float* __restrict__ b_right, float* __restrict__ left,
    _Float16* __restrict__ right_h) {
  __shared__ float stS[DSTATE];
  __shared__ float redS[4], redQ[4];
  __shared__ float part[4][64];
  const int l = blockIdx.x, tid = threadIdx.x;

  float x = state[l * DSTATE + tid];
  float s = x, q = x * x;
  #pragma unroll
  for (int o = 32; o > 0; o >>= 1) {
    s += __shfl_down(s, o);
    q += __shfl_down(q, o);
  }
  if ((tid & 63) == 0) { redS[tid >> 6] = s; redQ[tid >> 6] = q; }
  __syncthreads();
  float tot = redS[0] + redS[1] + redS[2] + redS[3];
  float totq = redQ[0] + redQ[1] + redQ[2] + redQ[3];
  float mean = tot * (1.0f / DSTATE);
  float var = totq * (1.0f / DSTATE) - mean * mean;
  float inv = rsqrtf(var + 1e-5f);
  stS[tid] = (x - mean) * inv * ln_w[tid] + ln_b[tid];
  __syncthreads();

  // Phase 2: output column j = tid&63 (j<32 -> left, else right), c-quarter
  // = tid>>6 (64 c each).
  const int j = tid & 63;
  const int quarter = tid >> 6;
  const float* __restrict__ w = (j < HH) ? (w_left + j) : (w_right + (j - HH));
  const int c0 = quarter * 64;
  float acc = 0.0f;
  #pragma unroll 8
  for (int cc = 0; cc < 64; ++cc) acc += stS[c0 + cc] * w[(c0 + cc) * HH];
  part[quarter][j] = acc;
  __syncthreads();
  if (tid < 64) {
    float sum = part[0][tid] + part[1][tid] + part[2][tid] + part[3][tid];
    if (tid < HH)
      left[l * HH + tid] = sum + b_left[tid];
    else
      right_h[l * HH + (tid - HH)] = (_Float16)(sum + b_right[tid - HH]);
  }
}

// ---- Kernel B: tT[l][p][j] = sum_i left[l][i]*Wg[i][j][p] (fp16), + w_rbfT --
// grid: 1024 blocks (16 jp-chunks x 64 l-chunks of 8) + 1 block for w_rbfT
__global__ __launch_bounds__(256) void prologB(
    const float* __restrict__ w_gate, const float* __restrict__ w_rbf,
    const float* __restrict__ left, _Float16* __restrict__ tT,
    _Float16* __restrict__ w_rbfT) {
  const int tid = threadIdx.x;
  if (blockIdx.x == 1024) {
    // w_rbfT[p][k] (128 x 64), zero-padded k in [36,64)
    for (int e = tid; e < DPAIR * 64; e += 256) {
      int p = e >> 6, k = e & 63;
      w_rbfT[e] = (k < DRBF) ? (_Float16)w_rbf[k * DPAIR + p] : (_Float16)0.0f;
    }
    return;
  }
  const int c = blockIdx.x & 15;   // jp-chunk (256 columns)
  const int lc = blockIdx.x >> 4;  // l-chunk (8 rows)
  const int j = tid & 31;
  const int p = c * 8 + (tid >> 5);

  float wcol[32];
  #pragma unroll
  for (int i = 0; i < 32; ++i) wcol[i] = w_gate[(i * HH + j) * DPAIR + p];

  const int l0 = lc * 8;
  #pragma unroll
  for (int l = l0; l < l0 + 8; ++l) {
    const float* __restrict__ lf = left + l * HH;  // wave-uniform -> s_loads
    float acc = 0.0f;
    #pragma unroll
    for (int i = 0; i < 32; ++i) acc += lf[i] * wcol[i];
    tT[l * (DPAIR * HH) + c * 256 + tid] = (_Float16)acc;
  }
}

// ---------------- Kernel C: main fused MFMA kernel ---------------------------
// grid 1024: block -> (l = bx>>1, m-half = bx&1). 256 threads = 4 waves.
// B-operands staged in LDS (24 KB) -> low VGPR pressure, no spills.
__global__ __launch_bounds__(256) void mainC(
    const float* __restrict__ xyz, const float* __restrict__ b_rbf,
    const float* __restrict__ b_gate, const _Float16* __restrict__ right_h,
    const _Float16* __restrict__ tT, const _Float16* __restrict__ w_rbfT,
    float* __restrict__ out) {
  __shared__ _Float16 sT[DPAIR * HH];   // 8 KB  : tT[l]  (p-major, 32 j)
  __shared__ _Float16 sW[DPAIR * 64];   // 16 KB : w_rbfT (p-major, 64 k)
  const int l = blockIdx.x >> 1;
  const int half = blockIdx.x & 1;
  const int tid = threadIdx.x;
  const int wave = tid >> 6;
  const int lane = tid & 63;
  const int ln16 = lane & 15;
  const int quad = lane >> 4;

  // Stage B-operands into LDS (coalesced uint4 copies)
  {
    const uint4* __restrict__ src = (const uint4*)(tT + (size_t)l * (DPAIR * HH));
    uint4* dst = (uint4*)sT;
    #pragma unroll
    for (int i = 0; i < 2; ++i) dst[tid + 256 * i] = src[tid + 256 * i];
    const uint4* __restrict__ src2 = (const uint4*)w_rbfT;
    uint4* dst2 = (uint4*)sW;
    #pragma unroll
    for (int i = 0; i < 4; ++i) dst2[tid + 256 * i] = src2[tid + 256 * i];
  }

  // cas_l (row a=1 of xyz[l])
  const float clx = xyz[l * 9 + 3];
  const float cly = xyz[l * 9 + 4];
  const float clz = xyz[l * 9 + 5];

  // Per-p biases for this lane's column (ln16 within each p-tile)
  float bg[8], br[8];
  #pragma unroll
  for (int pt = 0; pt < 8; ++pt) {
    bg[pt] = b_gate[pt * 16 + ln16];
    br[pt] = b_rbf[pt * 16 + ln16];
  }

  __syncthreads();

  const int mt0 = half * 16;
  for (int mt = mt0 + wave; mt < mt0 + 16; mt += 4) {
    const int mA = mt * 16 + ln16;  // A-operand row for this lane
    // right A-fragment (global, L2-hot, fully coalesced 1KB/wave)
    half8 Ar = *(const half8*)(right_h + mA * HH + quad * 8);

    // rbf A-fragments computed in registers (MFMA A-layout)
    const float dx = clx - xyz[mA * 9 + 3];
    const float dy = cly - xyz[mA * 9 + 4];
    const float dz = clz - xyz[mA * 9 + 5];
    const float d = sqrtf(fmaxf(dx * dx + dy * dy + dz * dz, 1e-12f));

    half8 A0, A1;
    #pragma unroll
    for (int jj = 0; jj < 8; ++jj) {
      const int k = quad * 8 + jj;
      const float u = (d - (2.0f + (float)k * MUSTEP)) * INVSIG;
      A0[jj] = (_Float16)__expf(-u * u);
    }
    #pragma unroll
    for (int jj = 0; jj < 8; ++jj) {
      const int k = 32 + quad * 8 + jj;
      float v = 0.0f;
      if (k < DRBF) {
        const float u = (d - (2.0f + (float)k * MUSTEP)) * INVSIG;
        v = __expf(-u * u);
      }
      A1[jj] = (_Float16)v;
    }

    #pragma unroll
    for (int pt = 0; pt < 8; ++pt) {
      const int p = pt * 16 + ln16;
      // B-fragments from LDS: quad-uniform per ln16 -> broadcast reads
      half8 Bt = *(const half8*)(sT + p * HH + quad * 8);
      half8 Bw0 = *(const half8*)(sW + p * 64 + quad * 8);
      half8 Bw1 = *(const half8*)(sW + p * 64 + 32 + quad * 8);

      floatx4 accL = {0.f, 0.f, 0.f, 0.f};
      floatx4 accR = {0.f, 0.f, 0.f, 0.f};
      accL = __builtin_amdgcn_mfma_f32_16x16x32_f16(Ar, Bt, accL, 0, 0, 0);
      accR = __builtin_amdgcn_mfma_f32_16x16x32_f16(A0, Bw0, accR, 0, 0, 0);
      accR = __builtin_amdgcn_mfma_f32_16x16x32_f16(A1, Bw1, accR, 0, 0, 0);

      float* orow = out + ((size_t)l * LSEQ + mt * 16 + quad * 4) * DPAIR + p;
      #pragma unroll
      for (int i = 0; i < 4; ++i) {
        const float logit = accL[i] + bg[pt];
        const float gate = __builtin_amdgcn_rcpf(1.0f + __expf(-logit));
        const float feat = accR[i] + br[pt];
        orow[i * DPAIR] = gate * feat;
      }
    }
  }
}

// ---------------- launch -----------------------------------------------------
extern "C" void kernel_launch(void* const* d_in, const int* in_sizes, int n_in,
                              void* d_out, int out_size, void* d_ws,
                              size_t ws_size, hipStream_t stream) {
  const float* xyz = (const float*)d_in[0];
  const float* state = (const float*)d_in[1];
  const float* ln_w = (const float*)d_in[2];
  const float* ln_b = (const float*)d_in[3];
  const float* w_rbf = (const float*)d_in[4];
  const float* b_rbf = (const float*)d_in[5];
  const float* w_left = (const float*)d_in[6];
  const float* b_left = (const float*)d_in[7];
  const float* w_right = (const float*)d_in[8];
  const float* b_right = (const float*)d_in[9];
  const float* w_gate = (const float*)d_in[10];
  const float* b_gate = (const float*)d_in[11];
  float* out = (float*)d_out;

  char* ws = (char*)d_ws;
  float* left = (float*)ws;                           // 512*32*4   = 65536 B
  _Float16* right_h = (_Float16*)(ws + 65536);        // 512*32*2   = 32768 B
  _Float16* tT = (_Float16*)(ws + 98304);             // 512*128*32*2 = 4 MB
  _Float16* w_rbfT = (_Float16*)(ws + 4292608);       // 128*64*2   = 16384 B

  prologA<<<512, 256, 0, stream>>>(state, ln_w, ln_b, w_left, b_left, w_right,
                                   b_right, left, right_h);
  prologB<<<1025, 256, 0, stream>>>(w_gate, w_rbf, left, tT, w_rbfT);
  mainC<<<1024, 256, 0, stream>>>(xyz, b_rbf, b_gate, right_h, tT, w_rbfT, out);
}

// Round 3
// 189.660 us; speedup vs baseline: 1.0172x; 1.0030x over previous
//
#include <hip/hip_runtime.h>
#include <hip/hip_fp16.h>

typedef _Float16 half8 __attribute__((ext_vector_type(8)));
typedef float floatx4 __attribute__((ext_vector_type(4)));

#define LSEQ 512
#define DSTATE 256
#define DPAIR 128
#define HH 32
#define DRBF 36

#define MUSTEP (20.0f / 35.0f)   // linspace(2,22,36) step
#define INVSIG 1.8f              // 1 / ((22-2)/36)

// ---------------- Kernel 1: fused prolog -------------------------------------
// grid 257. Blocks 0..255: two sequence rows each (l = 2*bx, 2*bx+1):
//   layernorm -> left/right projections -> t[l] = left @ Wg  (fp16, p-major)
// Block 256: transpose/pad w_rbf -> w_rbfT[p][k64].
__global__ __launch_bounds__(256) void prolog(
    const float* __restrict__ state, const float* __restrict__ ln_w,
    const float* __restrict__ ln_b, const float* __restrict__ w_left,
    const float* __restrict__ b_left, const float* __restrict__ w_right,
    const float* __restrict__ b_right, const float* __restrict__ w_gate,
    const float* __restrict__ w_rbf, _Float16* __restrict__ right_h,
    _Float16* __restrict__ tT, _Float16* __restrict__ w_rbfT) {
  const int tid = threadIdx.x;
  if (blockIdx.x == 256) {
    // w_rbfT[p][k] (128 x 64), zero-padded k in [36,64)
    for (int e = tid; e < DPAIR * 64; e += 256) {
      int p = e >> 6, k = e & 63;
      w_rbfT[e] = (k < DRBF) ? (_Float16)w_rbf[k * DPAIR + p] : (_Float16)0.0f;
    }
    return;
  }
  const int l0 = blockIdx.x * 2;

  __shared__ float stS[2][DSTATE];
  __shared__ float redS[2][4], redQ[2][4];
  __shared__ float part[2][4][64];
  __shared__ float sL[2][HH];
  __shared__ _Float16 sTT[2][DPAIR * HH];  // 16 KB, p-major

  // ---- layernorm, both rows
  float x0 = state[l0 * DSTATE + tid];
  float x1 = state[(l0 + 1) * DSTATE + tid];
  float s0 = x0, q0 = x0 * x0, s1 = x1, q1 = x1 * x1;
  #pragma unroll
  for (int o = 32; o > 0; o >>= 1) {
    s0 += __shfl_down(s0, o);
    q0 += __shfl_down(q0, o);
    s1 += __shfl_down(s1, o);
    q1 += __shfl_down(q1, o);
  }
  if ((tid & 63) == 0) {
    redS[0][tid >> 6] = s0; redQ[0][tid >> 6] = q0;
    redS[1][tid >> 6] = s1; redQ[1][tid >> 6] = q1;
  }
  __syncthreads();
  {
    const float lw = ln_w[tid], lb = ln_b[tid];
    float tot0 = redS[0][0] + redS[0][1] + redS[0][2] + redS[0][3];
    float totq0 = redQ[0][0] + redQ[0][1] + redQ[0][2] + redQ[0][3];
    float tot1 = redS[1][0] + redS[1][1] + redS[1][2] + redS[1][3];
    float totq1 = redQ[1][0] + redQ[1][1] + redQ[1][2] + redQ[1][3];
    float m0 = tot0 * (1.0f / DSTATE);
    float m1 = tot1 * (1.0f / DSTATE);
    float inv0 = rsqrtf(totq0 * (1.0f / DSTATE) - m0 * m0 + 1e-5f);
    float inv1 = rsqrtf(totq1 * (1.0f / DSTATE) - m1 * m1 + 1e-5f);
    stS[0][tid] = (x0 - m0) * inv0 * lw + lb;
    stS[1][tid] = (x1 - m1) * inv1 * lw + lb;
  }
  __syncthreads();

  // ---- left/right matvecs (4 partial threads per output column)
  {
    const int j = tid & 63, quarter = tid >> 6, c0 = quarter * 64;
    const float* __restrict__ w =
        (j < HH) ? (w_left + j) : (w_right + (j - HH));
    float a0 = 0.0f, a1 = 0.0f;
    #pragma unroll 8
    for (int cc = 0; cc < 64; ++cc) {
      const float wv = w[(c0 + cc) * HH];
      a0 += stS[0][c0 + cc] * wv;
      a1 += stS[1][c0 + cc] * wv;
    }
    part[0][quarter][j] = a0;
    part[1][quarter][j] = a1;
  }
  __syncthreads();
  if (tid < 128) {
    const int r = tid >> 6, jj = tid & 63;
    float sum = part[r][0][jj] + part[r][1][jj] + part[r][2][jj] + part[r][3][jj];
    if (jj < HH)
      sL[r][jj] = sum + b_left[jj];
    else
      right_h[(l0 + r) * HH + (jj - HH)] = (_Float16)(sum + b_right[jj - HH]);
  }
  __syncthreads();

  // ---- t[l][j][p] = sum_i left[l][i] * Wg[i][j][p]
  // thread: j = tid>>3 (0..31), pc = tid&7 -> 16 p values (pc*16..+15).
  // One float4 load instr = 8 consecutive 512B rows = 4KB contiguous.
  {
    const int j3 = tid >> 3;
    const int pc = tid & 7;
    float acc0[16], acc1[16];
    #pragma unroll
    for (int k = 0; k < 16; ++k) { acc0[k] = 0.0f; acc1[k] = 0.0f; }
    #pragma unroll 4
    for (int i = 0; i < 32; ++i) {
      const float la0 = sL[0][i], la1 = sL[1][i];
      const float4* __restrict__ wrow =
          (const float4*)(w_gate + (i * HH + j3) * DPAIR + pc * 16);
      float wv[16];
      *(float4*)(wv + 0) = wrow[0];
      *(float4*)(wv + 4) = wrow[1];
      *(float4*)(wv + 8) = wrow[2];
      *(float4*)(wv + 12) = wrow[3];
      #pragma unroll
      for (int k = 0; k < 16; ++k) {
        acc0[k] += la0 * wv[k];
        acc1[k] += la1 * wv[k];
      }
    }
    #pragma unroll
    for (int k = 0; k < 16; ++k) {
      const int p = pc * 16 + k;
      sTT[0][p * HH + j3] = (_Float16)acc0[k];
      sTT[1][p * HH + j3] = (_Float16)acc1[k];
    }
  }
  __syncthreads();

  // ---- coalesced store of both 8KB tiles
  {
    const uint4* __restrict__ s0p = (const uint4*)sTT[0];
    const uint4* __restrict__ s1p = (const uint4*)sTT[1];
    uint4* g0 = (uint4*)(tT + (size_t)l0 * (DPAIR * HH));
    uint4* g1 = (uint4*)(tT + (size_t)(l0 + 1) * (DPAIR * HH));
    g0[tid] = s0p[tid];
    g0[tid + 256] = s0p[tid + 256];
    g1[tid] = s1p[tid];
    g1[tid + 256] = s1p[tid + 256];
  }
}

// ---------------- Kernel 2: main fused MFMA kernel ---------------------------
// grid 1024: block -> (l = bx>>1, m-half = bx&1). 256 threads = 4 waves.
// tT[l] + w_rbfT staged in LDS; mt-invariant rbf B-fragments hoisted to regs.
__global__ __launch_bounds__(256) void mainC(
    const float* __restrict__ xyz, const float* __restrict__ b_rbf,
    const float* __restrict__ b_gate, const _Float16* __restrict__ right_h,
    const _Float16* __restrict__ tT, const _Float16* __restrict__ w_rbfT,
    float* __restrict__ out) {
  __shared__ _Float16 sT[DPAIR * HH];   // 8 KB  : tT[l]  (p-major, 32 j)
  __shared__ _Float16 sW[DPAIR * 64];   // 16 KB : w_rbfT (p-major, 64 k)
  const int l = blockIdx.x >> 1;
  const int half = blockIdx.x & 1;
  const int tid = threadIdx.x;
  const int wave = tid >> 6;
  const int lane = tid & 63;
  const int ln16 = lane & 15;
  const int quad = lane >> 4;

  // Stage B-operands into LDS (coalesced uint4 copies)
  {
    const uint4* __restrict__ src = (const uint4*)(tT + (size_t)l * (DPAIR * HH));
    uint4* dst = (uint4*)sT;
    #pragma unroll
    for (int i = 0; i < 2; ++i) dst[tid + 256 * i] = src[tid + 256 * i];
    const uint4* __restrict__ src2 = (const uint4*)w_rbfT;
    uint4* dst2 = (uint4*)sW;
    #pragma unroll
    for (int i = 0; i < 4; ++i) dst2[tid + 256 * i] = src2[tid + 256 * i];
  }

  // cas_l (row a=1 of xyz[l])
  const float clx = xyz[l * 9 + 3];
  const float cly = xyz[l * 9 + 4];
  const float clz = xyz[l * 9 + 5];

  // Per-p biases for this lane's column (ln16 within each p-tile)
  float bg[8], br[8];
  #pragma unroll
  for (int pt = 0; pt < 8; ++pt) {
    bg[pt] = b_gate[pt * 16 + ln16];
    br[pt] = b_rbf[pt * 16 + ln16];
  }

  __syncthreads();

  // mt-invariant rbf B-fragments -> registers (64 VGPRs)
  half8 Bw0[8], Bw1[8];
  #pragma unroll
  for (int pt = 0; pt < 8; ++pt) {
    const int p = pt * 16 + ln16;
    Bw0[pt] = *(const half8*)(sW + p * 64 + quad * 8);
    Bw1[pt] = *(const half8*)(sW + p * 64 + 32 + quad * 8);
  }

  const int mt0 = half * 16;
  for (int mt = mt0 + wave; mt < mt0 + 16; mt += 4) {
    const int mA = mt * 16 + ln16;  // A-operand row for this lane
    // right A-fragment (global, L2-hot, fully coalesced 1KB/wave)
    half8 Ar = *(const half8*)(right_h + mA * HH + quad * 8);

    // rbf A-fragments computed in registers (MFMA A-layout)
    const float dx = clx - xyz[mA * 9 + 3];
    const float dy = cly - xyz[mA * 9 + 4];
    const float dz = clz - xyz[mA * 9 + 5];
    const float d = sqrtf(fmaxf(dx * dx + dy * dy + dz * dz, 1e-12f));

    half8 A0, A1;
    #pragma unroll
    for (int jj = 0; jj < 8; ++jj) {
      const int k = quad * 8 + jj;
      const float u = (d - (2.0f + (float)k * MUSTEP)) * INVSIG;
      A0[jj] = (_Float16)__expf(-u * u);
    }
    #pragma unroll
    for (int jj = 0; jj < 8; ++jj) {
      const int k = 32 + quad * 8 + jj;
      float v = 0.0f;
      if (k < DRBF) {
        const float u = (d - (2.0f + (float)k * MUSTEP)) * INVSIG;
        v = __expf(-u * u);
      }
      A1[jj] = (_Float16)v;
    }

    #pragma unroll
    for (int pt = 0; pt < 8; ++pt) {
      const int p = pt * 16 + ln16;
      half8 Bt = *(const half8*)(sT + p * HH + quad * 8);

      floatx4 accL = {0.f, 0.f, 0.f, 0.f};
      floatx4 accR = {0.f, 0.f, 0.f, 0.f};
      accL = __builtin_amdgcn_mfma_f32_16x16x32_f16(Ar, Bt, accL, 0, 0, 0);
      accR = __builtin_amdgcn_mfma_f32_16x16x32_f16(A0, Bw0[pt], accR, 0, 0, 0);
      accR = __builtin_amdgcn_mfma_f32_16x16x32_f16(A1, Bw1[pt], accR, 0, 0, 0);

      float* orow = out + ((size_t)l * LSEQ + mt * 16 + quad * 4) * DPAIR + p;
      #pragma unroll
      for (int i = 0; i < 4; ++i) {
        const float logit = accL[i] + bg[pt];
        const float gate = __builtin_amdgcn_rcpf(1.0f + __expf(-logit));
        const float feat = accR[i] + br[pt];
        orow[i * DPAIR] = gate * feat;
      }
    }
  }
}

// ---------------- launch -----------------------------------------------------
extern "C" void kernel_launch(void* const* d_in, const int* in_sizes, int n_in,
                              void* d_out, int out_size, void* d_ws,
                              size_t ws_size, hipStream_t stream) {
  const float* xyz = (const float*)d_in[0];
  const float* state = (const float*)d_in[1];
  const float* ln_w = (const float*)d_in[2];
  const float* ln_b = (const float*)d_in[3];
  const float* w_rbf = (const float*)d_in[4];
  const float* b_rbf = (const float*)d_in[5];
  const float* w_left = (const float*)d_in[6];
  const float* b_left = (const float*)d_in[7];
  const float* w_right = (const float*)d_in[8];
  const float* b_right = (const float*)d_in[9];
  const float* w_gate = (const float*)d_in[10];
  const float* b_gate = (const float*)d_in[11];
  float* out = (float*)d_out;

  char* ws = (char*)d_ws;
  _Float16* right_h = (_Float16*)ws;                  // 512*32*2    = 32768 B
  _Float16* tT = (_Float16*)(ws + 32768);             // 512*128*32*2 = 4 MB
  _Float16* w_rbfT = (_Float16*)(ws + 32768 + 4194304);  // 128*64*2 = 16384 B

  prolog<<<257, 256, 0, stream>>>(state, ln_w, ln_b, w_left, b_left, w_right,
                                  b_right, w_gate, w_rbf, right_h, tT, w_rbfT);
  mainC<<<1024, 256, 0, stream>>>(xyz, b_rbf, b_gate, right_h, tT, w_rbfT, out);
}

// Round 4
// 189.231 us; speedup vs baseline: 1.0195x; 1.0023x over previous
//
#include <hip/hip_runtime.h>
#include <hip/hip_fp16.h>

typedef _Float16 half8 __attribute__((ext_vector_type(8)));
typedef float floatx4 __attribute__((ext_vector_type(4)));

#define LSEQ 512
#define DSTATE 256
#define DPAIR 128
#define HH 32
#define DRBF 36

#define MUSTEP (20.0f / 35.0f)   // linspace(2,22,36) step
#define INVSIG 1.8f              // 1 / ((22-2)/36)
#define OPAD 132                 // padded epilogue row (2-way LDS aliasing max)

// ---------------- Kernel 1: fused prolog -------------------------------------
// grid 257. Blocks 0..255: two sequence rows each (l = 2*bx, 2*bx+1):
//   layernorm -> left/right projections -> t[l] = left @ Wg  (fp16, p-major)
// Block 256: transpose/pad w_rbf -> w_rbfT[p][k64].
__global__ __launch_bounds__(256) void prolog(
    const float* __restrict__ state, const float* __restrict__ ln_w,
    const float* __restrict__ ln_b, const float* __restrict__ w_left,
    const float* __restrict__ b_left, const float* __restrict__ w_right,
    const float* __restrict__ b_right, const float* __restrict__ w_gate,
    const float* __restrict__ w_rbf, _Float16* __restrict__ right_h,
    _Float16* __restrict__ tT, _Float16* __restrict__ w_rbfT) {
  const int tid = threadIdx.x;
  if (blockIdx.x == 256) {
    // w_rbfT[p][k] (128 x 64), zero-padded k in [36,64)
    for (int e = tid; e < DPAIR * 64; e += 256) {
      int p = e >> 6, k = e & 63;
      w_rbfT[e] = (k < DRBF) ? (_Float16)w_rbf[k * DPAIR + p] : (_Float16)0.0f;
    }
    return;
  }
  const int l0 = blockIdx.x * 2;

  __shared__ float stS[2][DSTATE];
  __shared__ float redS[2][4], redQ[2][4];
  __shared__ float part[2][4][64];
  __shared__ float sL[2][HH];
  __shared__ _Float16 sTT[2][DPAIR * HH];  // 16 KB, p-major

  // ---- layernorm, both rows
  float x0 = state[l0 * DSTATE + tid];
  float x1 = state[(l0 + 1) * DSTATE + tid];
  float s0 = x0, q0 = x0 * x0, s1 = x1, q1 = x1 * x1;
  #pragma unroll
  for (int o = 32; o > 0; o >>= 1) {
    s0 += __shfl_down(s0, o);
    q0 += __shfl_down(q0, o);
    s1 += __shfl_down(s1, o);
    q1 += __shfl_down(q1, o);
  }
  if ((tid & 63) == 0) {
    redS[0][tid >> 6] = s0; redQ[0][tid >> 6] = q0;
    redS[1][tid >> 6] = s1; redQ[1][tid >> 6] = q1;
  }
  __syncthreads();
  {
    const float lw = ln_w[tid], lb = ln_b[tid];
    float tot0 = redS[0][0] + redS[0][1] + redS[0][2] + redS[0][3];
    float totq0 = redQ[0][0] + redQ[0][1] + redQ[0][2] + redQ[0][3];
    float tot1 = redS[1][0] + redS[1][1] + redS[1][2] + redS[1][3];
    float totq1 = redQ[1][0] + redQ[1][1] + redQ[1][2] + redQ[1][3];
    float m0 = tot0 * (1.0f / DSTATE);
    float m1 = tot1 * (1.0f / DSTATE);
    float inv0 = rsqrtf(totq0 * (1.0f / DSTATE) - m0 * m0 + 1e-5f);
    float inv1 = rsqrtf(totq1 * (1.0f / DSTATE) - m1 * m1 + 1e-5f);
    stS[0][tid] = (x0 - m0) * inv0 * lw + lb;
    stS[1][tid] = (x1 - m1) * inv1 * lw + lb;
  }
  __syncthreads();

  // ---- left/right matvecs (4 partial threads per output column)
  {
    const int j = tid & 63, quarter = tid >> 6, c0 = quarter * 64;
    const float* __restrict__ w =
        (j < HH) ? (w_left + j) : (w_right + (j - HH));
    float a0 = 0.0f, a1 = 0.0f;
    #pragma unroll 8
    for (int cc = 0; cc < 64; ++cc) {
      const float wv = w[(c0 + cc) * HH];
      a0 += stS[0][c0 + cc] * wv;
      a1 += stS[1][c0 + cc] * wv;
    }
    part[0][quarter][j] = a0;
    part[1][quarter][j] = a1;
  }
  __syncthreads();
  if (tid < 128) {
    const int r = tid >> 6, jj = tid & 63;
    float sum = part[r][0][jj] + part[r][1][jj] + part[r][2][jj] + part[r][3][jj];
    if (jj < HH)
      sL[r][jj] = sum + b_left[jj];
    else
      right_h[(l0 + r) * HH + (jj - HH)] = (_Float16)(sum + b_right[jj - HH]);
  }
  __syncthreads();

  // ---- t[l][j][p] = sum_i left[l][i] * Wg[i][j][p]
  // thread: j = tid>>3 (0..31), pc = tid&7 -> 16 p values (pc*16..+15).
  {
    const int j3 = tid >> 3;
    const int pc = tid & 7;
    float acc0[16], acc1[16];
    #pragma unroll
    for (int k = 0; k < 16; ++k) { acc0[k] = 0.0f; acc1[k] = 0.0f; }
    #pragma unroll 4
    for (int i = 0; i < 32; ++i) {
      const float la0 = sL[0][i], la1 = sL[1][i];
      const float4* __restrict__ wrow =
          (const float4*)(w_gate + (i * HH + j3) * DPAIR + pc * 16);
      float wv[16];
      *(float4*)(wv + 0) = wrow[0];
      *(float4*)(wv + 4) = wrow[1];
      *(float4*)(wv + 8) = wrow[2];
      *(float4*)(wv + 12) = wrow[3];
      #pragma unroll
      for (int k = 0; k < 16; ++k) {
        acc0[k] += la0 * wv[k];
        acc1[k] += la1 * wv[k];
      }
    }
    #pragma unroll
    for (int k = 0; k < 16; ++k) {
      const int p = pc * 16 + k;
      sTT[0][p * HH + j3] = (_Float16)acc0[k];
      sTT[1][p * HH + j3] = (_Float16)acc1[k];
    }
  }
  __syncthreads();

  // ---- coalesced store of both 8KB tiles
  {
    const uint4* __restrict__ s0p = (const uint4*)sTT[0];
    const uint4* __restrict__ s1p = (const uint4*)sTT[1];
    uint4* g0 = (uint4*)(tT + (size_t)l0 * (DPAIR * HH));
    uint4* g1 = (uint4*)(tT + (size_t)(l0 + 1) * (DPAIR * HH));
    g0[tid] = s0p[tid];
    g0[tid + 256] = s0p[tid + 256];
    g1[tid] = s1p[tid];
    g1[tid + 256] = s1p[tid + 256];
  }
}

// ---------------- Kernel 2: main fused MFMA kernel ---------------------------
// grid 512: one block per l. 256 threads = 4 waves; wave w does mt = w,w+4,..
// B-operands staged in LDS; epilogue transposed through wave-private LDS so
// global stores are fully-coalesced dwordx4 (1 KB per wave-instr).
__global__ __launch_bounds__(256) void mainC(
    const float* __restrict__ xyz, const float* __restrict__ b_rbf,
    const float* __restrict__ b_gate, const _Float16* __restrict__ right_h,
    const _Float16* __restrict__ tT, const _Float16* __restrict__ w_rbfT,
    float* __restrict__ out) {
  __shared__ _Float16 sT[DPAIR * HH];       // 8 KB  : tT[l] (p-major, 32 j)
  __shared__ _Float16 sW[DPAIR * 64];       // 16 KB : w_rbfT (p-major, 64 k)
  __shared__ float sOut[4][16 * OPAD];      // 33 KB : per-wave epilogue tiles
  const int l = blockIdx.x;
  const int tid = threadIdx.x;
  const int wave = tid >> 6;
  const int lane = tid & 63;
  const int ln16 = lane & 15;
  const int quad = lane >> 4;

  // Stage B-operands into LDS (coalesced uint4 copies)
  {
    const uint4* __restrict__ src = (const uint4*)(tT + (size_t)l * (DPAIR * HH));
    uint4* dst = (uint4*)sT;
    #pragma unroll
    for (int i = 0; i < 2; ++i) dst[tid + 256 * i] = src[tid + 256 * i];
    const uint4* __restrict__ src2 = (const uint4*)w_rbfT;
    uint4* dst2 = (uint4*)sW;
    #pragma unroll
    for (int i = 0; i < 4; ++i) dst2[tid + 256 * i] = src2[tid + 256 * i];
  }

  // cas_l (row a=1 of xyz[l])
  const float clx = xyz[l * 9 + 3];
  const float cly = xyz[l * 9 + 4];
  const float clz = xyz[l * 9 + 5];

  // Per-p biases for this lane's column (ln16 within each p-tile)
  float bg[8], br[8];
  #pragma unroll
  for (int pt = 0; pt < 8; ++pt) {
    bg[pt] = b_gate[pt * 16 + ln16];
    br[pt] = b_rbf[pt * 16 + ln16];
  }

  __syncthreads();

  // mt-invariant rbf B-fragments -> registers (64 VGPRs)
  half8 Bw0[8], Bw1[8];
  #pragma unroll
  for (int pt = 0; pt < 8; ++pt) {
    const int p = pt * 16 + ln16;
    Bw0[pt] = *(const half8*)(sW + p * 64 + quad * 8);
    Bw1[pt] = *(const half8*)(sW + p * 64 + 32 + quad * 8);
  }

  float* __restrict__ wtile = sOut[wave];

  for (int mt = wave; mt < 32; mt += 4) {
    const int mA = mt * 16 + ln16;  // A-operand row for this lane
    // right A-fragment (global, L2-hot, 1KB/wave coalesced)
    half8 Ar = *(const half8*)(right_h + mA * HH + quad * 8);

    // rbf A-fragments computed in registers (MFMA A-layout)
    const float dx = clx - xyz[mA * 9 + 3];
    const float dy = cly - xyz[mA * 9 + 4];
    const float dz = clz - xyz[mA * 9 + 5];
    const float d = sqrtf(fmaxf(dx * dx + dy * dy + dz * dz, 1e-12f));

    half8 A0, A1;
    #pragma unroll
    for (int jj = 0; jj < 8; ++jj) {
      const int k = quad * 8 + jj;
      const float u = (d - (2.0f + (float)k * MUSTEP)) * INVSIG;
      A0[jj] = (_Float16)__expf(-u * u);
    }
    #pragma unroll
    for (int jj = 0; jj < 8; ++jj) {
      const int k = 32 + quad * 8 + jj;
      float v = 0.0f;
      if (k < DRBF) {
        const float u = (d - (2.0f + (float)k * MUSTEP)) * INVSIG;
        v = __expf(-u * u);
      }
      A1[jj] = (_Float16)v;
    }

    #pragma unroll
    for (int pt = 0; pt < 8; ++pt) {
      const int p = pt * 16 + ln16;
      half8 Bt = *(const half8*)(sT + p * HH + quad * 8);

      floatx4 accL = {0.f, 0.f, 0.f, 0.f};
      floatx4 accR = {0.f, 0.f, 0.f, 0.f};
      accL = __builtin_amdgcn_mfma_f32_16x16x32_f16(Ar, Bt, accL, 0, 0, 0);
      accR = __builtin_amdgcn_mfma_f32_16x16x32_f16(A0, Bw0[pt], accR, 0, 0, 0);
      accR = __builtin_amdgcn_mfma_f32_16x16x32_f16(A1, Bw1[pt], accR, 0, 0, 0);

      // epilogue values -> wave-private LDS tile (row-padded, <=2-way banks)
      #pragma unroll
      for (int i = 0; i < 4; ++i) {
        const float logit = accL[i] + bg[pt];
        const float gate = __builtin_amdgcn_rcpf(1.0f + __expf(-logit));
        const float feat = accR[i] + br[pt];
        wtile[(quad * 4 + i) * OPAD + p] = gate * feat;
      }
    }

    // transpose-read + fully coalesced dwordx4 stores (wave-private: no barrier)
    {
      const int r2 = lane >> 5;   // 0..1
      const int c4 = lane & 31;   // 0..31 -> 4 consecutive floats
      float* __restrict__ obase =
          out + ((size_t)l * LSEQ + mt * 16) * DPAIR;
      #pragma unroll
      for (int it = 0; it < 8; ++it) {
        const int row = it * 2 + r2;
        const float4 v = *(const float4*)(wtile + row * OPAD + c4 * 4);
        *(float4*)(obase + row * DPAIR + c4 * 4) = v;
      }
    }
  }
}

// ---------------- launch -----------------------------------------------------
extern "C" void kernel_launch(void* const* d_in, const int* in_sizes, int n_in,
                              void* d_out, int out_size, void* d_ws,
                              size_t ws_size, hipStream_t stream) {
  const float* xyz = (const float*)d_in[0];
  const float* state = (const float*)d_in[1];
  const float* ln_w = (const float*)d_in[2];
  const float* ln_b = (const float*)d_in[3];
  const float* w_rbf = (const float*)d_in[4];
  const float* b_rbf = (const float*)d_in[5];
  const float* w_left = (const float*)d_in[6];
  const float* b_left = (const float*)d_in[7];
  const float* w_right = (const float*)d_in[8];
  const float* b_right = (const float*)d_in[9];
  const float* w_gate = (const float*)d_in[10];
  const float* b_gate = (const float*)d_in[11];
  float* out = (float*)d_out;

  char* ws = (char*)d_ws;
  _Float16* right_h = (_Float16*)ws;                  // 512*32*2    = 32768 B
  _Float16* tT = (_Float16*)(ws + 32768);             // 512*128*32*2 = 4 MB
  _Float16* w_rbfT = (_Float16*)(ws + 32768 + 4194304);  // 128*64*2 = 16384 B

  prolog<<<257, 256, 0, stream>>>(state, ln_w, ln_b, w_left, b_left, w_right,
                                  b_right, w_gate, w_rbf, right_h, tT, w_rbfT);
  mainC<<<512, 256, 0, stream>>>(xyz, b_rbf, b_gate, right_h, tT, w_rbfT, out);
}